// Round 2
// baseline (598.479 us; speedup 1.0000x reference)
//
#include <hip/hip_runtime.h>

#define BB 64
#define TT 1024
#define HH 512
#define KMIX 10
#define UU 64
#define VV 80
#define SDIM 3
#define OUTW (HH + VV + SDIM)  // 595

// ---------------- Kernel 1: abk = exp(X@W + b); fused copy of x-part + stroke-part to out ----------------
#define ROWS 16
__global__ __launch_bounds__(256) void k1_gemm(
    const float* __restrict__ x,       // [B*T, H]
    const float* __restrict__ stroke,  // [B*T, 3]
    const float* __restrict__ Wm,      // [H, 30]
    const float* __restrict__ bias,    // [30]
    float* __restrict__ out,           // [B*T, 595]
    float* __restrict__ abk)           // [B*T, 30]
{
    __shared__ float xs[ROWS][HH + 4];  // stride 516 floats: float4-aligned, rows offset 4 banks -> max 2-way (free)
    const int tid = threadIdx.x;
    const int r0 = blockIdx.x * ROWS;

    // Cooperative load of X tile (16x512 = 2048 float4), fused store of x-part to out.
    const float4* x4 = (const float4*)(x + (size_t)r0 * HH);
    #pragma unroll
    for (int i = 0; i < 8; ++i) {
        int f4 = tid + i * 256;
        float4 v = x4[f4];
        int row = f4 >> 7;          // / (512/4)
        int h4 = (f4 & 127) << 2;
        *(float4*)&xs[row][h4] = v;
        float* orow = out + (size_t)(r0 + row) * OUTW + h4;  // row stride 595: not 16B aligned -> scalar stores
        orow[0] = v.x; orow[1] = v.y; orow[2] = v.z; orow[3] = v.w;
    }
    // stroke part: 16 rows x 3
    if (tid < ROWS * SDIM) {
        int row = tid / SDIM, c = tid % SDIM;
        out[(size_t)(r0 + row) * OUTW + HH + VV + c] = stroke[(size_t)(r0 + row) * SDIM + c];
    }
    __syncthreads();

    // GEMM: 16 rows x 15 j-pairs = 240 tasks (one per thread)
    if (tid < ROWS * 15) {
        int row = tid / 15;
        int jp = tid % 15;
        const float2* W2 = (const float2*)Wm;  // [H][15] float2, 8B-aligned
        float acc0 = 0.f, acc1 = 0.f;
        #pragma unroll 8
        for (int h = 0; h < HH; ++h) {
            float v = xs[row][h];            // LDS broadcast within row-group
            float2 w = W2[h * 15 + jp];      // L1/L2-resident (61 KB total)
            acc0 += v * w.x;
            acc1 += v * w.y;
        }
        int j = jp * 2;
        float e0 = expf(acc0 + bias[j]);
        float e1 = expf(acc1 + bias[j + 1]);
        float* arow = abk + (size_t)(r0 + row) * 30;
        arow[j] = e0;
        arow[j + 1] = e1;
    }
}

// ---------------- Kernel 2: inclusive prefix-scan of kappa_hat over T, per (b,k), + kappa0 ----------------
__global__ __launch_bounds__(64) void k2_scan(
    float* __restrict__ abk,            // [B*T, 30]; scans columns 20..29 in place
    const float* __restrict__ kappa0)   // [B, K, 1]
{
    const int b = blockIdx.x / KMIX;
    const int k = blockIdx.x % KMIX;
    const int lane = threadIdx.x;
    const size_t base = (size_t)b * TT * 30 + 20 + k;
    const int t0 = lane * 16;

    float v[16];
    #pragma unroll
    for (int i = 0; i < 16; ++i) v[i] = abk[base + (size_t)(t0 + i) * 30];
    #pragma unroll
    for (int i = 1; i < 16; ++i) v[i] += v[i - 1];

    float total = v[15];
    float xinc = total;
    #pragma unroll
    for (int off = 1; off < 64; off <<= 1) {
        float y = __shfl_up(xinc, off, 64);
        if (lane >= off) xinc += y;
    }
    float excl = xinc - total + kappa0[b * KMIX + k];

    #pragma unroll
    for (int i = 0; i < 16; ++i) abk[base + (size_t)(t0 + i) * 30] = v[i] + excl;
}

// ---------------- Kernel 3: phi (Gaussian mixture over u) + window = phi @ char, write window-part ----------------
#define TCHUNK 64
__global__ __launch_bounds__(256) void k3_window(
    const float* __restrict__ abk,  // [B*T, 30] (kappa slots now cumulative)
    const float* __restrict__ ch,   // [B, U, V]
    float* __restrict__ out)        // [B*T, 595]
{
    __shared__ float cs[UU * VV];   // 5120 floats = 20 KB
    const int b = blockIdx.x / (TT / TCHUNK);
    const int tc = blockIdx.x % (TT / TCHUNK);
    const int tid = threadIdx.x;

    const float4* c4 = (const float4*)(ch + (size_t)b * UU * VV);
    #pragma unroll
    for (int i = tid; i < UU * VV / 4; i += 256)
        *(float4*)&cs[i * 4] = c4[i];
    __syncthreads();

    const int wave = tid >> 6;
    const int lane = tid & 63;
    const float uf = (float)lane;
    const int v2 = 64 + (lane & 15);

    for (int t = wave; t < TCHUNK; t += 4) {
        const int row = b * TT + tc * TCHUNK + t;
        float val = 0.f;
        if (lane < 30) val = abk[(size_t)row * 30 + lane];

        // phi[u=lane] = sum_k alpha_k * exp(-beta_k * (kappa_k - u)^2)
        float phi = 0.f;
        #pragma unroll
        for (int k = 0; k < KMIX; ++k) {
            float a  = __shfl(val, k, 64);
            float be = __shfl(val, 10 + k, 64);
            float kp = __shfl(val, 20 + k, 64);
            float d = kp - uf;
            phi += a * __expf(-be * d * d);
        }

        // window[v] = sum_u phi[u] * char[b,u,v]; shuffle-broadcast phi
        float acc1 = 0.f, acc2 = 0.f;
        #pragma unroll 16
        for (int u = 0; u < UU; ++u) {
            float p = __shfl(phi, u, 64);
            acc1 += p * cs[u * VV + lane];   // v = lane (0..63): consecutive -> conflict-free
            acc2 += p * cs[u * VV + v2];     // v = 64..79: 4-lane same-addr broadcast -> conflict-free
        }

        float* orow = out + (size_t)row * OUTW + HH;
        orow[lane] = acc1;
        if (lane < 16) orow[64 + lane] = acc2;
    }
}

extern "C" void kernel_launch(void* const* d_in, const int* in_sizes, int n_in,
                              void* d_out, int out_size, void* d_ws, size_t ws_size,
                              hipStream_t stream) {
    const float* input0   = (const float*)d_in[0];  // [B,T,H]
    const float* stroke   = (const float*)d_in[1];  // [B,T,3]
    const float* chars    = (const float*)d_in[2];  // [B,U,V]
    const float* window_w = (const float*)d_in[3];  // [H,30]
    const float* window_b = (const float*)d_in[4];  // [30]
    const float* kappa0   = (const float*)d_in[5];  // [B,K,1]
    float* out = (float*)d_out;
    float* abk = (float*)d_ws;  // [B*T, 30] = 7.86 MB scratch

    k1_gemm<<<dim3(BB * TT / ROWS), dim3(256), 0, stream>>>(input0, stroke, window_w, window_b, out, abk);
    k2_scan<<<dim3(BB * KMIX), dim3(64), 0, stream>>>(abk, kappa0);
    k3_window<<<dim3(BB * (TT / TCHUNK)), dim3(256), 0, stream>>>(abk, chars, out);
}

// Round 3
// 356.411 us; speedup vs baseline: 1.6792x; 1.6792x over previous
//
#include <hip/hip_runtime.h>

#define BB 64
#define TT 1024
#define HH 512
#define KMIX 10
#define UU 64
#define VV 80
#define SDIM 3
#define OUTW (HH + VV + SDIM)  // 595
#define ROWS 16

// ---------------- kW: transpose W [512,30] -> Wt [30,512] (tiny, runs once) ----------------
__global__ __launch_bounds__(256) void kW_transpose(const float* __restrict__ Wm, float* __restrict__ Wt) {
    int idx = blockIdx.x * 256 + threadIdx.x;
    if (idx < 30 * HH) {
        int j = idx >> 9, h = idx & 511;
        Wt[idx] = Wm[h * 30 + j];
    }
}

// ---------------- k1: abk = exp(X@Wt^T + b); fused coalesced copy of x/stroke to out ----------------
// 512 threads. W read ONCE per block into registers (8 float4/thread), amortized over 16 rows.
__global__ __launch_bounds__(512, 4) void k1_gemm(
    const float* __restrict__ x,       // [B*T, H]
    const float* __restrict__ stroke,  // [B*T, 3]
    const float* __restrict__ Wt,      // [30, 512] transposed
    const float* __restrict__ bias,    // [30]
    float* __restrict__ out,           // [B*T, 595]
    float* __restrict__ abk)           // [B*T, 30]
{
    __shared__ float xs[ROWS][HH + 4];  // 33 KB; reused as partial buffer after GEMM reads finish
    const int tid = threadIdx.x;
    const int r0 = blockIdx.x * ROWS;

    // Stage X tile (16x512) in LDS via float4.
    const float4* x4 = (const float4*)(x + (size_t)r0 * HH);
    #pragma unroll
    for (int i = 0; i < 4; ++i) {
        int f4 = tid + (i << 9);
        float4 v = x4[f4];
        *(float4*)&xs[f4 >> 7][(f4 & 127) << 2] = v;
    }
    if (tid < ROWS * SDIM) {
        int row = tid / SDIM, c = tid % SDIM;
        out[(size_t)(r0 + row) * OUTW + HH + VV + c] = stroke[(size_t)(r0 + row) * SDIM + c];
    }
    __syncthreads();

    // Coalesced x-part copy: each store instr = 64 consecutive dwords.
    #pragma unroll
    for (int i = 0; i < 16; ++i) {
        int idx = tid + (i << 9);
        out[(size_t)(r0 + (idx >> 9)) * OUTW + (idx & 511)] = xs[idx >> 9][idx & 511];
    }

    // GEMM partials: thread = (hc, j), hc=h-chunk of 32, j=0..29. W chunk in registers.
    const bool active = tid < 480;
    float acc[ROWS];
    int j = 0, hc = 0;
    if (active) {
        hc = tid / 30;
        j = tid % 30;
        const float4* wp = (const float4*)(Wt + j * HH + hc * 32);
        float4 w4[8];
        #pragma unroll
        for (int q = 0; q < 8; ++q) w4[q] = wp[q];
        #pragma unroll
        for (int r = 0; r < ROWS; ++r) {
            const float4* xp = (const float4*)&xs[r][hc * 32];  // broadcast: ~3 distinct addrs/wave
            float s = 0.f;
            #pragma unroll
            for (int q = 0; q < 8; ++q) {
                float4 xv = xp[q];
                s += xv.x * w4[q].x + xv.y * w4[q].y + xv.z * w4[q].z + xv.w * w4[q].w;
            }
            acc[r] = s;
        }
    }
    __syncthreads();                 // all xs reads done -> safe to reuse as partials
    float* plds = &xs[0][0];         // [r][hc][j]: r*480 + hc*30 + j  (30 KB < 33 KB)
    if (active) {
        #pragma unroll
        for (int r = 0; r < ROWS; ++r) plds[r * 480 + tid] = acc[r];  // consecutive lanes -> conflict-free
    }
    __syncthreads();
    if (tid < ROWS * 30) {
        int row = tid / 30, jj = tid % 30;
        float s = 0.f;
        #pragma unroll
        for (int q = 0; q < 16; ++q) s += plds[row * 480 + q * 30 + jj];  // 480%32==0: ~2-way, free
        abk[(size_t)(r0 + row) * 30 + jj] = expf(s + bias[jj]);
    }
}

// ---------------- k2: inclusive prefix-scan of kappa_hat over T per (b,k), + kappa0 ----------------
__global__ __launch_bounds__(64) void k2_scan(
    float* __restrict__ abk, const float* __restrict__ kappa0)
{
    const int b = blockIdx.x / KMIX;
    const int k = blockIdx.x % KMIX;
    const int lane = threadIdx.x;
    const size_t base = (size_t)b * TT * 30 + 20 + k;
    const int t0 = lane * 16;

    float v[16];
    #pragma unroll
    for (int i = 0; i < 16; ++i) v[i] = abk[base + (size_t)(t0 + i) * 30];
    #pragma unroll
    for (int i = 1; i < 16; ++i) v[i] += v[i - 1];

    float total = v[15];
    float xinc = total;
    #pragma unroll
    for (int off = 1; off < 64; off <<= 1) {
        float y = __shfl_up(xinc, off, 64);
        if (lane >= off) xinc += y;
    }
    float excl = xinc - total + kappa0[b * KMIX + k];

    #pragma unroll
    for (int i = 0; i < 16; ++i) abk[base + (size_t)(t0 + i) * 30] = v[i] + excl;
}

// ---------------- k3: phi + window = phi @ char, b128 LDS reads, no shuffles in hot loop ----------------
#define TCHUNK 64
__global__ __launch_bounds__(256) void k3_window(
    const float* __restrict__ abk,  // [B*T, 30] (kappa cumulative)
    const float* __restrict__ ch,   // [B, U, V]
    float* __restrict__ out)        // [B*T, 595]
{
    __shared__ float cs[VV][68];      // char transposed [v][u], stride 68 (272B, 16B-aligned): 21.8 KB
    __shared__ float ab[TCHUNK][32];  // abk rows padded 30->32: 8 KB
    __shared__ float ph[4][64];       // phi per wave: 1 KB
    const int b = blockIdx.x / (TT / TCHUNK);
    const int tc = blockIdx.x % (TT / TCHUNK);
    const int tid = threadIdx.x;
    const int wave = tid >> 6, lane = tid & 63;

    const float* cb = ch + (size_t)b * UU * VV;
    for (int i = tid; i < UU * VV; i += 256) {       // coalesced read, transposed write (once)
        cs[i % VV][i / VV] = cb[i];
    }
    const float* ab_g = abk + (size_t)(b * TT + tc * TCHUNK) * 30;
    for (int i = tid; i < TCHUNK * 30; i += 256) {
        ab[i / 30][i % 30] = ab_g[i];
    }
    __syncthreads();

    const float uf = (float)lane;
    const float* csr1 = cs[lane];
    const float* csr2 = cs[64 + (lane & 15)];

    for (int t = wave; t < TCHUNK; t += 4) {
        // abk row via 8 broadcast b128 reads -> registers (static indexing only)
        float r_[32];
        #pragma unroll
        for (int q = 0; q < 8; ++q) {
            float4 v4 = *(const float4*)&ab[t][q * 4];
            r_[q * 4] = v4.x; r_[q * 4 + 1] = v4.y; r_[q * 4 + 2] = v4.z; r_[q * 4 + 3] = v4.w;
        }
        // phi[u=lane]
        float phi = 0.f;
        #pragma unroll
        for (int k = 0; k < KMIX; ++k) {
            float d = r_[20 + k] - uf;
            phi += r_[k] * __expf(-r_[10 + k] * d * d);
        }
        ph[wave][lane] = phi;  // same-wave write->read: compiler inserts lgkmcnt wait

        // window: v=lane (b128), v2=64+(lane&15) (16 distinct x4 dup)
        float acc1 = 0.f, acc2 = 0.f;
        #pragma unroll
        for (int g = 0; g < 16; ++g) {
            float4 p4 = *(const float4*)&ph[wave][g * 4];  // broadcast
            float4 c1 = *(const float4*)&csr1[g * 4];
            float4 c2 = *(const float4*)&csr2[g * 4];
            acc1 += p4.x * c1.x + p4.y * c1.y + p4.z * c1.z + p4.w * c1.w;
            acc2 += p4.x * c2.x + p4.y * c2.y + p4.z * c2.z + p4.w * c2.w;
        }
        float* orow = out + (size_t)(b * TT + tc * TCHUNK + t) * OUTW + HH;
        orow[lane] = acc1;
        if (lane < 16) orow[64 + lane] = acc2;
    }
}

extern "C" void kernel_launch(void* const* d_in, const int* in_sizes, int n_in,
                              void* d_out, int out_size, void* d_ws, size_t ws_size,
                              hipStream_t stream) {
    const float* input0   = (const float*)d_in[0];
    const float* stroke   = (const float*)d_in[1];
    const float* chars    = (const float*)d_in[2];
    const float* window_w = (const float*)d_in[3];
    const float* window_b = (const float*)d_in[4];
    const float* kappa0   = (const float*)d_in[5];
    float* out = (float*)d_out;
    float* abk = (float*)d_ws;                                  // [B*T,30] = 7.86 MB
    float* Wt  = (float*)((char*)d_ws + (size_t)BB * TT * 30 * 4);  // [30,512] = 61 KB

    kW_transpose<<<dim3((30 * HH + 255) / 256), dim3(256), 0, stream>>>(window_w, Wt);
    k1_gemm<<<dim3(BB * TT / ROWS), dim3(512), 0, stream>>>(input0, stroke, Wt, window_b, out, abk);
    k2_scan<<<dim3(BB * KMIX), dim3(64), 0, stream>>>(abk, kappa0);
    k3_window<<<dim3(BB * (TT / TCHUNK)), dim3(256), 0, stream>>>(abk, chars, out);
}